// Round 5
// baseline (3786.450 us; speedup 1.0000x reference)
//
#include <hip/hip_runtime.h>
#include <hip/hip_bf16.h>
#include <math.h>

// PaiNN layer: N=50000 nodes, E=800000 edges, H=128, R=20.
// Round 5: occupancy fix. Edge kernel goes 512 threads / 64 edges / 2 rows
// per thread (VGPR<=128, LDS 73.5KB) -> 2 blocks/CU = 16 waves/CU (was 8).
// All LDS strides multiple of 4 floats -> float4 LDS ops; k-loops unrolled.
// Pipeline: counting-sort edges by dst, edge kernel with LDS segmented
// reduce + few atomics, node kernel finishes in place over d_out.

#define H 128
#define R 20
#define KX (H + R)          // 148
#define LN_EPS 1e-5f

#define BE 64               // edges per block
#define XS_STRIDE 152       // mult of 8 -> float4-aligned rows, bank-spread
#define H1_STRIDE 136       // mult of 8

#define BN 64               // nodes per block (node kernel)
#define US_STRIDE 257
#define H2_STRIDE 129

__device__ __forceinline__ float silu_f(float x) {
    return x / (1.0f + __expf(-x));
}

__global__ __launch_bounds__(256)
void zero_f4_kernel(float4* __restrict__ p, long n4)
{
    const long stride = (long)gridDim.x * blockDim.x;
    for (long i = (long)blockIdx.x * blockDim.x + threadIdx.x; i < n4; i += stride)
        p[i] = make_float4(0.f, 0.f, 0.f, 0.f);
}

__global__ __launch_bounds__(256)
void zero_i_kernel(int* __restrict__ p, int n)
{
    const int stride = gridDim.x * blockDim.x;
    for (int i = blockIdx.x * blockDim.x + threadIdx.x; i < n; i += stride)
        p[i] = 0;
}

__global__ __launch_bounds__(256)
void hist_kernel(const int* __restrict__ eidx, int E, int* __restrict__ cnt)
{
    const int stride = gridDim.x * blockDim.x;
    for (int i = blockIdx.x * blockDim.x + threadIdx.x; i < E; i += stride)
        atomicAdd(&cnt[eidx[E + i]], 1);
}

__global__ __launch_bounds__(1024, 1)
void scan_kernel(const int* __restrict__ cnt, int N, int* __restrict__ fill)
{
    __shared__ int lds[1024];
    __shared__ int base_s;
    const int tid = threadIdx.x;
    if (tid == 0) base_s = 0;
    __syncthreads();
    const int nchunk = (N + 1023) >> 10;
    for (int c = 0; c < nchunk; ++c) {
        const int i   = (c << 10) + tid;
        const int val = (i < N) ? cnt[i] : 0;
        lds[tid] = val;
        __syncthreads();
        for (int off = 1; off < 1024; off <<= 1) {      // Hillis-Steele inclusive
            int t = (tid >= off) ? lds[tid - off] : 0;
            __syncthreads();
            lds[tid] += t;
            __syncthreads();
        }
        const int incl = lds[tid];
        if (i < N) fill[i] = base_s + (incl - val);     // exclusive
        __syncthreads();
        if (tid == 1023) base_s += incl;                // chunk total
        __syncthreads();
    }
}

__global__ __launch_bounds__(256)
void scatter_kernel(const int* __restrict__ eidx, int E,
                    int* __restrict__ fill, int* __restrict__ sorted)
{
    const int stride = gridDim.x * blockDim.x;
    for (int i = blockIdx.x * blockDim.x + threadIdx.x; i < E; i += stride) {
        const int d    = eidx[E + i];
        const int slot = atomicAdd(&fill[d], 1);
        sorted[slot] = i;
    }
}

__global__ __launch_bounds__(512, 4)
void painn_edge_kernel(const float* __restrict__ s,
                       const float* __restrict__ v,
                       const float* __restrict__ rbf,
                       const float* __restrict__ evu,
                       const float* __restrict__ mW1,
                       const float* __restrict__ mb1,
                       const float* __restrict__ mW2,
                       const float* __restrict__ mb2,
                       const int*   __restrict__ eidx,
                       const int*   __restrict__ sorted,
                       int E,
                       float* __restrict__ agg_s,   // [N,H]   (d_out part 0)
                       float* __restrict__ agg_v)   // [N,3,H] (d_out part 1)
{
    __shared__ float Xs[BE * XS_STRIDE];   // x-tile for GEMM1, then reduce stage
    __shared__ float H1s[BE * H1_STRIDE];
    __shared__ float evus[BE][3];
    __shared__ int   eids[BE];
    __shared__ int   srcs[BE];
    __shared__ int   dsts[BE];

    const int t  = threadIdx.x;
    const int e0 = blockIdx.x * BE;

    if (t < BE) {
        const int e = sorted[e0 + t];
        eids[t] = e;
        srcs[t] = eidx[e];               // edge_index row 0
        dsts[t] = eidx[E + e];           // edge_index row 1 (sorted)
    }
    __syncthreads();

    if (t < BE * 3) {
        int r = t / 3, c = t - r * 3;
        evus[r][c] = evu[eids[r] * 3 + c];
    }

    // ---- gather x = [s[src], rbf] into Xs ----
    #pragma unroll
    for (int it = 0; it < 4; ++it) {
        int idx = t + it * 512;          // 0..2047 -> 64 rows x 32 float4
        int row = idx >> 5;
        int c4  = (idx & 31) << 2;
        const float4 val = *reinterpret_cast<const float4*>(s + srcs[row] * H + c4);
        *reinterpret_cast<float4*>(&Xs[row * XS_STRIDE + c4]) = val;
    }
    #pragma unroll
    for (int it = 0; it < 3; ++it) {
        int idx = t + it * 512;          // 0..1279 -> 64 rows x 20
        if (idx < BE * R) {
            int row = idx / R;
            int c   = idx - row * R;
            Xs[row * XS_STRIDE + H + c] = rbf[eids[row] * R + c];
        }
    }
    __syncthreads();

    const int ty  = t >> 4;              // 0..31
    const int tx  = t & 15;              // 0..15
    const int jb  = tx << 3;             // output col base (8 cols/thread)
    const int er0 = ty << 1;             // edge row base (2 edges/thread)
    const int er1 = er0 + 1;

    // reducer mapping: 4 groups x 16 rows, each thread owns one column
    const int rcol = t & 127;
    const int rr0  = (t >> 7) << 4;

    // ---- GEMM1: h1 = silu(x @ mW1 + mb1) ----
    {
        float acc0[8], acc1[8];
        #pragma unroll
        for (int j = 0; j < 8; ++j) { acc0[j] = 0.f; acc1[j] = 0.f; }

        const float* wp = mW1 + jb;
        for (int k = 0; k < KX; k += 4) {        // 148 = 4*37
            const float4 xa = *reinterpret_cast<const float4*>(&Xs[er0 * XS_STRIDE + k]);
            const float4 xb = *reinterpret_cast<const float4*>(&Xs[er1 * XS_STRIDE + k]);
            const float xav[4] = {xa.x, xa.y, xa.z, xa.w};
            const float xbv[4] = {xb.x, xb.y, xb.z, xb.w};
            #pragma unroll
            for (int kk = 0; kk < 4; ++kk) {
                const float4 w0 = *reinterpret_cast<const float4*>(wp + kk * H);
                const float4 w1 = *reinterpret_cast<const float4*>(wp + kk * H + 4);
                const float wj[8] = {w0.x, w0.y, w0.z, w0.w, w1.x, w1.y, w1.z, w1.w};
                #pragma unroll
                for (int j = 0; j < 8; ++j) {
                    acc0[j] += xav[kk] * wj[j];
                    acc1[j] += xbv[kk] * wj[j];
                }
            }
            wp += 4 * H;
        }
        const float4 b0 = *reinterpret_cast<const float4*>(mb1 + jb);
        const float4 b1 = *reinterpret_cast<const float4*>(mb1 + jb + 4);
        const float bias[8] = {b0.x, b0.y, b0.z, b0.w, b1.x, b1.y, b1.z, b1.w};
        float4 o0, o1;
        o0.x = silu_f(acc0[0] + bias[0]); o0.y = silu_f(acc0[1] + bias[1]);
        o0.z = silu_f(acc0[2] + bias[2]); o0.w = silu_f(acc0[3] + bias[3]);
        o1.x = silu_f(acc0[4] + bias[4]); o1.y = silu_f(acc0[5] + bias[5]);
        o1.z = silu_f(acc0[6] + bias[6]); o1.w = silu_f(acc0[7] + bias[7]);
        *reinterpret_cast<float4*>(&H1s[er0 * H1_STRIDE + jb])     = o0;
        *reinterpret_cast<float4*>(&H1s[er0 * H1_STRIDE + jb + 4]) = o1;
        o0.x = silu_f(acc1[0] + bias[0]); o0.y = silu_f(acc1[1] + bias[1]);
        o0.z = silu_f(acc1[2] + bias[2]); o0.w = silu_f(acc1[3] + bias[3]);
        o1.x = silu_f(acc1[4] + bias[4]); o1.y = silu_f(acc1[5] + bias[5]);
        o1.z = silu_f(acc1[6] + bias[6]); o1.w = silu_f(acc1[7] + bias[7]);
        *reinterpret_cast<float4*>(&H1s[er1 * H1_STRIDE + jb])     = o0;
        *reinterpret_cast<float4*>(&H1s[er1 * H1_STRIDE + jb + 4]) = o1;
    }
    __syncthreads();   // H1s ready; Xs reads done -> Xs reusable as stage

    // ---- GEMM2 chunk 0: a_ss -> stage in Xs -> segmented reduce -> agg_s ----
    {
        float acc0[8], acc1[8];
        #pragma unroll
        for (int j = 0; j < 8; ++j) { acc0[j] = 0.f; acc1[j] = 0.f; }

        const float* wp = mW2 + jb;
        for (int k = 0; k < H; k += 4) {         // 128 = 4*32
            const float4 ha = *reinterpret_cast<const float4*>(&H1s[er0 * H1_STRIDE + k]);
            const float4 hb = *reinterpret_cast<const float4*>(&H1s[er1 * H1_STRIDE + k]);
            const float hav[4] = {ha.x, ha.y, ha.z, ha.w};
            const float hbv[4] = {hb.x, hb.y, hb.z, hb.w};
            #pragma unroll
            for (int kk = 0; kk < 4; ++kk) {
                const float4 w0 = *reinterpret_cast<const float4*>(wp + kk * 3 * H);
                const float4 w1 = *reinterpret_cast<const float4*>(wp + kk * 3 * H + 4);
                const float wj[8] = {w0.x, w0.y, w0.z, w0.w, w1.x, w1.y, w1.z, w1.w};
                #pragma unroll
                for (int j = 0; j < 8; ++j) {
                    acc0[j] += hav[kk] * wj[j];
                    acc1[j] += hbv[kk] * wj[j];
                }
            }
            wp += 4 * 3 * H;
        }
        const float4 b0 = *reinterpret_cast<const float4*>(mb2 + jb);
        const float4 b1 = *reinterpret_cast<const float4*>(mb2 + jb + 4);
        float4 o0, o1;
        o0.x = acc0[0] + b0.x; o0.y = acc0[1] + b0.y;
        o0.z = acc0[2] + b0.z; o0.w = acc0[3] + b0.w;
        o1.x = acc0[4] + b1.x; o1.y = acc0[5] + b1.y;
        o1.z = acc0[6] + b1.z; o1.w = acc0[7] + b1.w;
        *reinterpret_cast<float4*>(&Xs[er0 * XS_STRIDE + jb])     = o0;
        *reinterpret_cast<float4*>(&Xs[er0 * XS_STRIDE + jb + 4]) = o1;
        o0.x = acc1[0] + b0.x; o0.y = acc1[1] + b0.y;
        o0.z = acc1[2] + b0.z; o0.w = acc1[3] + b0.w;
        o1.x = acc1[4] + b1.x; o1.y = acc1[5] + b1.y;
        o1.z = acc1[6] + b1.z; o1.w = acc1[7] + b1.w;
        *reinterpret_cast<float4*>(&Xs[er1 * XS_STRIDE + jb])     = o0;
        *reinterpret_cast<float4*>(&Xs[er1 * XS_STRIDE + jb + 4]) = o1;
        __syncthreads();

        // segmented run-sum over 16 rows per thread; flush on dst change
        float run = 0.f;
        int prev = dsts[rr0];
        for (int r = rr0; r < rr0 + 16; ++r) {
            const int d = dsts[r];
            if (d != prev) {
                unsafeAtomicAdd(&agg_s[prev * H + rcol], run);
                run = 0.f; prev = d;
            }
            run += Xs[r * XS_STRIDE + rcol];
        }
        unsafeAtomicAdd(&agg_s[prev * H + rcol], run);
    }
    __syncthreads();

    // ---- GEMM2 chunks 1&2: a_sv, a_vv; per-d combine -> stage -> reduce ----
    {
        float asv0[8], asv1[8], avv0[8], avv1[8];
        #pragma unroll
        for (int j = 0; j < 8; ++j) {
            asv0[j] = 0.f; asv1[j] = 0.f; avv0[j] = 0.f; avv1[j] = 0.f;
        }

        const float* wp = mW2 + H + jb;       // cols [128..256) and [256..384)
        for (int k = 0; k < H; k += 2) {
            const float2 ha = *reinterpret_cast<const float2*>(&H1s[er0 * H1_STRIDE + k]);
            const float2 hb = *reinterpret_cast<const float2*>(&H1s[er1 * H1_STRIDE + k]);
            const float hav[2] = {ha.x, ha.y};
            const float hbv[2] = {hb.x, hb.y};
            #pragma unroll
            for (int kk = 0; kk < 2; ++kk) {
                const float4 s0 = *reinterpret_cast<const float4*>(wp + kk * 3 * H);
                const float4 s1 = *reinterpret_cast<const float4*>(wp + kk * 3 * H + 4);
                const float4 v0 = *reinterpret_cast<const float4*>(wp + kk * 3 * H + H);
                const float4 v1 = *reinterpret_cast<const float4*>(wp + kk * 3 * H + H + 4);
                const float ws[8] = {s0.x, s0.y, s0.z, s0.w, s1.x, s1.y, s1.z, s1.w};
                const float wv[8] = {v0.x, v0.y, v0.z, v0.w, v1.x, v1.y, v1.z, v1.w};
                #pragma unroll
                for (int j = 0; j < 8; ++j) {
                    asv0[j] += hav[kk] * ws[j];  avv0[j] += hav[kk] * wv[j];
                    asv1[j] += hbv[kk] * ws[j];  avv1[j] += hbv[kk] * wv[j];
                }
            }
            wp += 2 * 3 * H;
        }
        const float4 bs0 = *reinterpret_cast<const float4*>(mb2 + H + jb);
        const float4 bs1 = *reinterpret_cast<const float4*>(mb2 + H + jb + 4);
        const float4 bv0 = *reinterpret_cast<const float4*>(mb2 + 2 * H + jb);
        const float4 bv1 = *reinterpret_cast<const float4*>(mb2 + 2 * H + jb + 4);
        const float bsv[8] = {bs0.x, bs0.y, bs0.z, bs0.w, bs1.x, bs1.y, bs1.z, bs1.w};
        const float bvv[8] = {bv0.x, bv0.y, bv0.z, bv0.w, bv1.x, bv1.y, bv1.z, bv1.w};
        #pragma unroll
        for (int j = 0; j < 8; ++j) {
            asv0[j] += bsv[j];  avv0[j] += bvv[j];
            asv1[j] += bsv[j];  avv1[j] += bvv[j];
        }

        #pragma unroll
        for (int d = 0; d < 3; ++d) {
            // owners: msg = a_sv*evu_d + a_vv*v[src][d]  -> stage in Xs
            {
                const float ed0 = evus[er0][d];
                const float ed1 = evus[er1][d];
                const float* vp0 = v + ((size_t)srcs[er0] * 3 + d) * H + jb;
                const float* vp1 = v + ((size_t)srcs[er1] * 3 + d) * H + jb;
                const float4 va0 = *reinterpret_cast<const float4*>(vp0);
                const float4 va1 = *reinterpret_cast<const float4*>(vp0 + 4);
                const float4 vb0 = *reinterpret_cast<const float4*>(vp1);
                const float4 vb1 = *reinterpret_cast<const float4*>(vp1 + 4);
                float4 o;
                o.x = asv0[0] * ed0 + avv0[0] * va0.x;
                o.y = asv0[1] * ed0 + avv0[1] * va0.y;
                o.z = asv0[2] * ed0 + avv0[2] * va0.z;
                o.w = asv0[3] * ed0 + avv0[3] * va0.w;
                *reinterpret_cast<float4*>(&Xs[er0 * XS_STRIDE + jb]) = o;
                o.x = asv0[4] * ed0 + avv0[4] * va1.x;
                o.y = asv0[5] * ed0 + avv0[5] * va1.y;
                o.z = asv0[6] * ed0 + avv0[6] * va1.z;
                o.w = asv0[7] * ed0 + avv0[7] * va1.w;
                *reinterpret_cast<float4*>(&Xs[er0 * XS_STRIDE + jb + 4]) = o;
                o.x = asv1[0] * ed1 + avv1[0] * vb0.x;
                o.y = asv1[1] * ed1 + avv1[1] * vb0.y;
                o.z = asv1[2] * ed1 + avv1[2] * vb0.z;
                o.w = asv1[3] * ed1 + avv1[3] * vb0.w;
                *reinterpret_cast<float4*>(&Xs[er1 * XS_STRIDE + jb]) = o;
                o.x = asv1[4] * ed1 + avv1[4] * vb1.x;
                o.y = asv1[5] * ed1 + avv1[5] * vb1.y;
                o.z = asv1[6] * ed1 + avv1[6] * vb1.z;
                o.w = asv1[7] * ed1 + avv1[7] * vb1.w;
                *reinterpret_cast<float4*>(&Xs[er1 * XS_STRIDE + jb + 4]) = o;
            }
            __syncthreads();

            // reducers: segmented run-sum into agg_v[(dst*3+d)*H + col]
            float run = 0.f;
            int prev = dsts[rr0];
            for (int r = rr0; r < rr0 + 16; ++r) {
                const int dn = dsts[r];
                if (dn != prev) {
                    unsafeAtomicAdd(&agg_v[((size_t)prev * 3 + d) * H + rcol], run);
                    run = 0.f; prev = dn;
                }
                run += Xs[r * XS_STRIDE + rcol];
            }
            unsafeAtomicAdd(&agg_v[((size_t)prev * 3 + d) * H + rcol], run);
            __syncthreads();
        }
    }
}

__global__ __launch_bounds__(256, 1)
void painn_node_kernel(const float* __restrict__ s,
                       const float* __restrict__ v,
                       const float* __restrict__ uW1,
                       const float* __restrict__ ub1,
                       const float* __restrict__ uW2,
                       const float* __restrict__ ub2,
                       const float* __restrict__ ln_g,
                       const float* __restrict__ ln_b,
                       int N,
                       float* __restrict__ out_s,   // in: agg_s, out: s_out
                       float* __restrict__ out_v)   // in: agg_v, out: v_out
{
    __shared__ float Us[BN * US_STRIDE];   // [64][256+pad] : [s+agg_s | v_norm], later y
    __shared__ float H2s[BN * H2_STRIDE];

    const int t  = threadIdx.x;
    const int n0 = blockIdx.x * BN;
    const int m  = min(BN, N - n0);

    // ---- load s+agg_s and compute v_norm into Us ----
    #pragma unroll
    for (int it = 0; it < 8; ++it) {
        int idx = t + it * 256;
        int row = idx >> 5;
        int c4  = (idx & 31) << 2;
        if (row < m) {
            const int nb = (n0 + row) * H + c4;
            const float4 sv = *reinterpret_cast<const float4*>(s + nb);
            const float4 av = *reinterpret_cast<const float4*>(out_s + nb);
            float* p = &Us[row * US_STRIDE + c4];
            p[0] = sv.x + av.x; p[1] = sv.y + av.y;
            p[2] = sv.z + av.z; p[3] = sv.w + av.w;

            float nx = 0.f, ny = 0.f, nz = 0.f, nw = 0.f;
            #pragma unroll
            for (int d = 0; d < 3; ++d) {
                const int vb = ((n0 + row) * 3 + d) * H + c4;
                const float4 vv = *reinterpret_cast<const float4*>(v + vb);
                const float4 avv = *reinterpret_cast<const float4*>(out_v + vb);
                const float a0 = vv.x + avv.x, a1 = vv.y + avv.y;
                const float a2 = vv.z + avv.z, a3 = vv.w + avv.w;
                nx += a0 * a0; ny += a1 * a1; nz += a2 * a2; nw += a3 * a3;
            }
            float* q = &Us[row * US_STRIDE + H + c4];
            q[0] = sqrtf(nx); q[1] = sqrtf(ny); q[2] = sqrtf(nz); q[3] = sqrtf(nw);
        }
    }
    __syncthreads();

    const int ty = t >> 4;
    const int tx = t & 15;
    const int jb = tx << 3;
    const int nr = ty << 2;

    // ---- GEMV1: silu(upd_in @ uW1 + ub1) -> H2s ----
    {
        float acc[4][8];
        #pragma unroll
        for (int r2 = 0; r2 < 4; ++r2)
            #pragma unroll
            for (int j = 0; j < 8; ++j) acc[r2][j] = 0.f;

        const float* wp = uW1 + jb;
        for (int k = 0; k < 2 * H; ++k) {
            const float4 w0 = *reinterpret_cast<const float4*>(wp);
            const float4 w1 = *reinterpret_cast<const float4*>(wp + 4);
            wp += H;
            float uk[4];
            #pragma unroll
            for (int r2 = 0; r2 < 4; ++r2) uk[r2] = Us[(nr + r2) * US_STRIDE + k];
            #pragma unroll
            for (int r2 = 0; r2 < 4; ++r2) {
                acc[r2][0] += uk[r2] * w0.x;
                acc[r2][1] += uk[r2] * w0.y;
                acc[r2][2] += uk[r2] * w0.z;
                acc[r2][3] += uk[r2] * w0.w;
                acc[r2][4] += uk[r2] * w1.x;
                acc[r2][5] += uk[r2] * w1.y;
                acc[r2][6] += uk[r2] * w1.z;
                acc[r2][7] += uk[r2] * w1.w;
            }
        }
        const float4 b0 = *reinterpret_cast<const float4*>(ub1 + jb);
        const float4 b1 = *reinterpret_cast<const float4*>(ub1 + jb + 4);
        const float bias[8] = {b0.x, b0.y, b0.z, b0.w, b1.x, b1.y, b1.z, b1.w};
        #pragma unroll
        for (int r2 = 0; r2 < 4; ++r2)
            #pragma unroll
            for (int j = 0; j < 8; ++j)
                H2s[(nr + r2) * H2_STRIDE + jb + j] = silu_f(acc[r2][j] + bias[j]);
    }
    __syncthreads();

    // ---- GEMV2: delta_s & gate; y = s + delta_s into Us ----
    float gate[4][8];
    {
        float ad[4][8], ag[4][8];
        #pragma unroll
        for (int r2 = 0; r2 < 4; ++r2)
            #pragma unroll
            for (int j = 0; j < 8; ++j) { ad[r2][j] = 0.f; ag[r2][j] = 0.f; }

        const float* wp = uW2 + jb;
        for (int k = 0; k < H; ++k) {
            const float4 d0 = *reinterpret_cast<const float4*>(wp);
            const float4 d1 = *reinterpret_cast<const float4*>(wp + 4);
            const float4 g0 = *reinterpret_cast<const float4*>(wp + H);
            const float4 g1 = *reinterpret_cast<const float4*>(wp + H + 4);
            wp += 2 * H;
            float hk[4];
            #pragma unroll
            for (int r2 = 0; r2 < 4; ++r2) hk[r2] = H2s[(nr + r2) * H2_STRIDE + k];
            #pragma unroll
            for (int r2 = 0; r2 < 4; ++r2) {
                ad[r2][0] += hk[r2] * d0.x;  ag[r2][0] += hk[r2] * g0.x;
                ad[r2][1] += hk[r2] * d0.y;  ag[r2][1] += hk[r2] * g0.y;
                ad[r2][2] += hk[r2] * d0.z;  ag[r2][2] += hk[r2] * g0.z;
                ad[r2][3] += hk[r2] * d0.w;  ag[r2][3] += hk[r2] * g0.w;
                ad[r2][4] += hk[r2] * d1.x;  ag[r2][4] += hk[r2] * g1.x;
                ad[r2][5] += hk[r2] * d1.y;  ag[r2][5] += hk[r2] * g1.y;
                ad[r2][6] += hk[r2] * d1.z;  ag[r2][6] += hk[r2] * g1.z;
                ad[r2][7] += hk[r2] * d1.w;  ag[r2][7] += hk[r2] * g1.w;
            }
        }
        const float4 bd0 = *reinterpret_cast<const float4*>(ub2 + jb);
        const float4 bd1 = *reinterpret_cast<const float4*>(ub2 + jb + 4);
        const float4 bg0 = *reinterpret_cast<const float4*>(ub2 + H + jb);
        const float4 bg1 = *reinterpret_cast<const float4*>(ub2 + H + jb + 4);
        const float bd[8] = {bd0.x, bd0.y, bd0.z, bd0.w, bd1.x, bd1.y, bd1.z, bd1.w};
        const float bg[8] = {bg0.x, bg0.y, bg0.z, bg0.w, bg1.x, bg1.y, bg1.z, bg1.w};

        #pragma unroll
        for (int r2 = 0; r2 < 4; ++r2) {
            #pragma unroll
            for (int j = 0; j < 8; ++j) gate[r2][j] = ag[r2][j] + bg[j];
            if (nr + r2 < m) {
                const int nb = (n0 + nr + r2) * H + jb;
                const float4 s0 = *reinterpret_cast<const float4*>(s + nb);
                const float4 s1 = *reinterpret_cast<const float4*>(s + nb + 4);
                const float sl[8] = {s0.x, s0.y, s0.z, s0.w, s1.x, s1.y, s1.z, s1.w};
                float* yp = &Us[(nr + r2) * US_STRIDE + jb];
                #pragma unroll
                for (int j = 0; j < 8; ++j) yp[j] = sl[j] + ad[r2][j] + bd[j];
            }
        }
    }
    __syncthreads();

    // ---- LayerNorm on y (4 threads per row) -> s_out ----
    {
        const int row = t >> 2;
        const int q   = t & 3;
        if (row < m) {
            float sum = 0.f, ss = 0.f;
            #pragma unroll
            for (int i = 0; i < 32; ++i) {
                const float val = Us[row * US_STRIDE + q * 32 + i];
                sum += val; ss += val * val;
            }
            sum += __shfl_xor(sum, 1); ss += __shfl_xor(ss, 1);
            sum += __shfl_xor(sum, 2); ss += __shfl_xor(ss, 2);
            const float mu   = sum * (1.0f / H);
            const float var  = ss * (1.0f / H) - mu * mu;
            const float rstd = rsqrtf(fmaxf(var, 0.f) + LN_EPS);
            #pragma unroll
            for (int i4 = 0; i4 < 8; ++i4) {
                const int c = q * 32 + i4 * 4;
                const float4 g = *reinterpret_cast<const float4*>(ln_g + c);
                const float4 b = *reinterpret_cast<const float4*>(ln_b + c);
                const float* yp = &Us[row * US_STRIDE + c];
                float4 o;
                o.x = (yp[0] - mu) * rstd * g.x + b.x;
                o.y = (yp[1] - mu) * rstd * g.y + b.y;
                o.z = (yp[2] - mu) * rstd * g.z + b.z;
                o.w = (yp[3] - mu) * rstd * g.w + b.w;
                *reinterpret_cast<float4*>(out_s + (n0 + row) * H + c) = o;
            }
        }
    }

    // ---- v_out = gate * (v + agg_v), in place over agg_v ----
    #pragma unroll
    for (int r2 = 0; r2 < 4; ++r2) {
        if (nr + r2 < m) {
            const int nn = n0 + nr + r2;
            #pragma unroll
            for (int d = 0; d < 3; ++d) {
                const int vb = (nn * 3 + d) * H + jb;
                const float4 vv0 = *reinterpret_cast<const float4*>(v + vb);
                const float4 vv1 = *reinterpret_cast<const float4*>(v + vb + 4);
                const float4 av0 = *reinterpret_cast<const float4*>(out_v + vb);
                const float4 av1 = *reinterpret_cast<const float4*>(out_v + vb + 4);
                float4 o0, o1;
                o0.x = gate[r2][0] * (vv0.x + av0.x);
                o0.y = gate[r2][1] * (vv0.y + av0.y);
                o0.z = gate[r2][2] * (vv0.z + av0.z);
                o0.w = gate[r2][3] * (vv0.w + av0.w);
                o1.x = gate[r2][4] * (vv1.x + av1.x);
                o1.y = gate[r2][5] * (vv1.y + av1.y);
                o1.z = gate[r2][6] * (vv1.z + av1.z);
                o1.w = gate[r2][7] * (vv1.w + av1.w);
                *reinterpret_cast<float4*>(out_v + vb)     = o0;
                *reinterpret_cast<float4*>(out_v + vb + 4) = o1;
            }
        }
    }
}

extern "C" void kernel_launch(void* const* d_in, const int* in_sizes, int n_in,
                              void* d_out, int out_size, void* d_ws, size_t ws_size,
                              hipStream_t stream)
{
    const float* s    = (const float*)d_in[0];
    const float* v    = (const float*)d_in[1];
    const float* rbf  = (const float*)d_in[2];
    const float* evu  = (const float*)d_in[3];
    const float* mW1  = (const float*)d_in[4];
    const float* mb1  = (const float*)d_in[5];
    const float* mW2  = (const float*)d_in[6];
    const float* mb2  = (const float*)d_in[7];
    const float* uW1  = (const float*)d_in[8];
    const float* ub1  = (const float*)d_in[9];
    const float* uW2  = (const float*)d_in[10];
    const float* ub2  = (const float*)d_in[11];
    const float* ln_g = (const float*)d_in[12];
    const float* ln_b = (const float*)d_in[13];
    const int*   eidx = (const int*)d_in[14];

    const int N = in_sizes[0] / H;   // 50000
    const int E = in_sizes[2] / R;   // 800000

    float* agg_s = (float*)d_out;                 // [N,H]
    float* agg_v = (float*)d_out + (size_t)N * H; // [N,3,H]

    // workspace layout: cnt[N] | fill[N] | sorted[E]  (~3.6 MB)
    int* cnt    = (int*)d_ws;
    int* fill   = cnt + N;
    int* sorted = fill + N;

    // zero agg buffers (d_out re-poisoned to 0xAA before every call) + counters
    const long n4 = (long)N * 4 * H / 4;          // float4 count
    zero_f4_kernel<<<dim3(2048), dim3(256), 0, stream>>>((float4*)d_out, n4);
    zero_i_kernel<<<dim3(64), dim3(256), 0, stream>>>(cnt, N);

    // counting sort of edges by destination
    hist_kernel<<<dim3(2048), dim3(256), 0, stream>>>(eidx, E, cnt);
    scan_kernel<<<dim3(1), dim3(1024), 0, stream>>>(cnt, N, fill);
    scatter_kernel<<<dim3(2048), dim3(256), 0, stream>>>(eidx, E, fill, sorted);

    painn_edge_kernel<<<dim3(E / BE), dim3(512), 0, stream>>>(
        s, v, rbf, evu, mW1, mb1, mW2, mb2, eidx, sorted, E, agg_s, agg_v);

    painn_node_kernel<<<dim3((N + BN - 1) / BN), dim3(256), 0, stream>>>(
        s, v, uW1, ub1, uW2, ub2, ln_g, ln_b, N, agg_s, agg_v);
}

// Round 6
// 2635.216 us; speedup vs baseline: 1.4369x; 1.4369x over previous
//
#include <hip/hip_runtime.h>
#include <hip/hip_bf16.h>
#include <math.h>

// PaiNN layer: N=50000 nodes, E=800000 edges, H=128, R=20.
// Round 6: kill redundant weight streaming (R4/R5 were L2-BW-bound on
// weights: traffic = threads*cols_per_thread*K*4B; R5 doubled it -> 1.65x
// slower, proving the model). New mapping: wave = 16 edge rows, lane = 2
// output cols. X/H1 LDS reads are wave-uniform broadcasts (free); weight
// redundancy 16x -> 4x (per wave, and all 4 waves read identical addrs ->
// L1 catches most). Pipeline: counting-sort by dst, edge kernel with LDS
// segmented reduce + few atomics, node kernel finishes in place.

#define H 128
#define R 20
#define KX (H + R)          // 148
#define LN_EPS 1e-5f

#define BE 64               // edges per block
#define XS_STRIDE 152       // mult of 8 -> float4-aligned rows
#define H1_STRIDE 136       // mult of 8

#define BN 64               // nodes per block (node kernel)
#define US_STRIDE 257
#define H2_STRIDE 129

__device__ __forceinline__ float silu_f(float x) {
    return x / (1.0f + __expf(-x));
}

__global__ __launch_bounds__(256)
void zero_f4_kernel(float4* __restrict__ p, long n4)
{
    const long stride = (long)gridDim.x * blockDim.x;
    for (long i = (long)blockIdx.x * blockDim.x + threadIdx.x; i < n4; i += stride)
        p[i] = make_float4(0.f, 0.f, 0.f, 0.f);
}

__global__ __launch_bounds__(256)
void zero_i_kernel(int* __restrict__ p, int n)
{
    const int stride = gridDim.x * blockDim.x;
    for (int i = blockIdx.x * blockDim.x + threadIdx.x; i < n; i += stride)
        p[i] = 0;
}

__global__ __launch_bounds__(256)
void hist_kernel(const int* __restrict__ eidx, int E, int* __restrict__ cnt)
{
    const int stride = gridDim.x * blockDim.x;
    for (int i = blockIdx.x * blockDim.x + threadIdx.x; i < E; i += stride)
        atomicAdd(&cnt[eidx[E + i]], 1);
}

__global__ __launch_bounds__(1024, 1)
void scan_kernel(const int* __restrict__ cnt, int N, int* __restrict__ fill)
{
    __shared__ int lds[1024];
    __shared__ int base_s;
    const int tid = threadIdx.x;
    if (tid == 0) base_s = 0;
    __syncthreads();
    const int nchunk = (N + 1023) >> 10;
    for (int c = 0; c < nchunk; ++c) {
        const int i   = (c << 10) + tid;
        const int val = (i < N) ? cnt[i] : 0;
        lds[tid] = val;
        __syncthreads();
        for (int off = 1; off < 1024; off <<= 1) {      // Hillis-Steele inclusive
            int t = (tid >= off) ? lds[tid - off] : 0;
            __syncthreads();
            lds[tid] += t;
            __syncthreads();
        }
        const int incl = lds[tid];
        if (i < N) fill[i] = base_s + (incl - val);     // exclusive
        __syncthreads();
        if (tid == 1023) base_s += incl;                // chunk total
        __syncthreads();
    }
}

__global__ __launch_bounds__(256)
void scatter_kernel(const int* __restrict__ eidx, int E,
                    int* __restrict__ fill, int* __restrict__ sorted)
{
    const int stride = gridDim.x * blockDim.x;
    for (int i = blockIdx.x * blockDim.x + threadIdx.x; i < E; i += stride) {
        const int d    = eidx[E + i];
        const int slot = atomicAdd(&fill[d], 1);
        sorted[slot] = i;
    }
}

__global__ __launch_bounds__(256, 2)
void painn_edge_kernel(const float* __restrict__ s,
                       const float* __restrict__ v,
                       const float* __restrict__ rbf,
                       const float* __restrict__ evu,
                       const float* __restrict__ mW1,
                       const float* __restrict__ mb1,
                       const float* __restrict__ mW2,
                       const float* __restrict__ mb2,
                       const int*   __restrict__ eidx,
                       const int*   __restrict__ sorted,
                       int E,
                       float* __restrict__ agg_s,   // [N,H]   (d_out part 0)
                       float* __restrict__ agg_v)   // [N,3,H] (d_out part 1)
{
    __shared__ float Xs[BE * XS_STRIDE];   // x-tile, then a_ss stage, then a_sv stage
    __shared__ float H1s[BE * H1_STRIDE];  // h1, then msg_v stage
    __shared__ float evus[BE][3];
    __shared__ int   eids[BE];
    __shared__ int   srcs[BE];
    __shared__ int   dsts[BE];

    const int t  = threadIdx.x;
    const int e0 = blockIdx.x * BE;

    if (t < BE) {
        const int e = sorted[e0 + t];
        eids[t] = e;
        srcs[t] = eidx[e];               // edge_index row 0
        dsts[t] = eidx[E + e];           // edge_index row 1 (sorted)
    }
    __syncthreads();

    if (t < BE * 3) {
        int r = t / 3, c = t - r * 3;
        evus[r][c] = evu[(size_t)eids[r] * 3 + c];
    }

    // ---- gather x = [s[src], rbf] into Xs ----
    #pragma unroll
    for (int it = 0; it < 8; ++it) {
        int idx = t + it * 256;          // 0..2047 -> 64 rows x 32 float4
        int row = idx >> 5;
        int c4  = (idx & 31) << 2;
        const float4 val = *reinterpret_cast<const float4*>(s + (size_t)srcs[row] * H + c4);
        *reinterpret_cast<float4*>(&Xs[row * XS_STRIDE + c4]) = val;
    }
    #pragma unroll
    for (int it = 0; it < 5; ++it) {
        int idx = t + it * 256;          // 0..1279 -> 64 rows x 20
        int row = idx / R;
        int c   = idx - row * R;
        Xs[row * XS_STRIDE + H + c] = rbf[(size_t)eids[row] * R + c];
    }
    __syncthreads();

    const int lane = t & 63;             // 0..63
    const int wid  = t >> 6;             // wave 0..3
    const int er0  = wid << 4;           // 16 edge rows per wave
    const int c0   = lane << 1;          // 2 output cols per lane

    // reducer mapping: 2 groups x 32 rows, each thread owns one column
    const int rcol = t & 127;
    const int rr0  = (t >> 7) << 5;

    float2 acc[16];

    // ---- GEMM1: h1 = silu(x @ mW1 + mb1) -> H1s (own rows, all cols) ----
    #pragma unroll
    for (int r = 0; r < 16; ++r) acc[r] = make_float2(0.f, 0.f);
    {
        const float* wp = mW1 + c0;
        for (int k = 0; k < KX; k += 4) {            // 148 = 4*37
            const float2 w0 = *reinterpret_cast<const float2*>(wp);
            const float2 w1 = *reinterpret_cast<const float2*>(wp + H);
            const float2 w2 = *reinterpret_cast<const float2*>(wp + 2 * H);
            const float2 w3 = *reinterpret_cast<const float2*>(wp + 3 * H);
            wp += 4 * H;
            #pragma unroll
            for (int r = 0; r < 16; ++r) {           // broadcast LDS reads
                const float4 x = *reinterpret_cast<const float4*>(&Xs[(er0 + r) * XS_STRIDE + k]);
                acc[r].x += x.x * w0.x + x.y * w1.x + x.z * w2.x + x.w * w3.x;
                acc[r].y += x.x * w0.y + x.y * w1.y + x.z * w2.y + x.w * w3.y;
            }
        }
        const float2 b = *reinterpret_cast<const float2*>(mb1 + c0);
        #pragma unroll
        for (int r = 0; r < 16; ++r) {
            float2 o;
            o.x = silu_f(acc[r].x + b.x);
            o.y = silu_f(acc[r].y + b.y);
            *reinterpret_cast<float2*>(&H1s[(er0 + r) * H1_STRIDE + c0]) = o;
        }
    }
    // no barrier: each wave wrote & reads only its own H1s rows

    // ---- chunk0: a_ss -> stage in Xs -> segmented reduce -> agg_s ----
    #pragma unroll
    for (int r = 0; r < 16; ++r) acc[r] = make_float2(0.f, 0.f);
    {
        const float* wp = mW2 + c0;                  // cols [0,128)
        for (int k = 0; k < H; k += 4) {             // 128 = 4*32
            const float2 w0 = *reinterpret_cast<const float2*>(wp);
            const float2 w1 = *reinterpret_cast<const float2*>(wp + 3 * H);
            const float2 w2 = *reinterpret_cast<const float2*>(wp + 6 * H);
            const float2 w3 = *reinterpret_cast<const float2*>(wp + 9 * H);
            wp += 12 * H;
            #pragma unroll
            for (int r = 0; r < 16; ++r) {
                const float4 h = *reinterpret_cast<const float4*>(&H1s[(er0 + r) * H1_STRIDE + k]);
                acc[r].x += h.x * w0.x + h.y * w1.x + h.z * w2.x + h.w * w3.x;
                acc[r].y += h.x * w0.y + h.y * w1.y + h.z * w2.y + h.w * w3.y;
            }
        }
        const float2 b = *reinterpret_cast<const float2*>(mb2 + c0);
        #pragma unroll
        for (int r = 0; r < 16; ++r) {
            float2 o;
            o.x = acc[r].x + b.x;
            o.y = acc[r].y + b.y;
            *reinterpret_cast<float2*>(&Xs[(er0 + r) * XS_STRIDE + c0]) = o;
        }
    }
    __syncthreads();
    {
        float run = 0.f;
        int prev = dsts[rr0];
        for (int r = rr0; r < rr0 + 32; ++r) {
            const int d = dsts[r];
            if (d != prev) {
                unsafeAtomicAdd(&agg_s[(size_t)prev * H + rcol], run);
                run = 0.f; prev = d;
            }
            run += Xs[r * XS_STRIDE + rcol];
        }
        unsafeAtomicAdd(&agg_s[(size_t)prev * H + rcol], run);
    }
    __syncthreads();

    // ---- sv-pass: a_sv -> stage into Xs (read back thread-locally) ----
    #pragma unroll
    for (int r = 0; r < 16; ++r) acc[r] = make_float2(0.f, 0.f);
    {
        const float* wp = mW2 + H + c0;              // cols [128,256)
        for (int k = 0; k < H; k += 4) {
            const float2 w0 = *reinterpret_cast<const float2*>(wp);
            const float2 w1 = *reinterpret_cast<const float2*>(wp + 3 * H);
            const float2 w2 = *reinterpret_cast<const float2*>(wp + 6 * H);
            const float2 w3 = *reinterpret_cast<const float2*>(wp + 9 * H);
            wp += 12 * H;
            #pragma unroll
            for (int r = 0; r < 16; ++r) {
                const float4 h = *reinterpret_cast<const float4*>(&H1s[(er0 + r) * H1_STRIDE + k]);
                acc[r].x += h.x * w0.x + h.y * w1.x + h.z * w2.x + h.w * w3.x;
                acc[r].y += h.x * w0.y + h.y * w1.y + h.z * w2.y + h.w * w3.y;
            }
        }
        const float2 b = *reinterpret_cast<const float2*>(mb2 + H + c0);
        #pragma unroll
        for (int r = 0; r < 16; ++r) {
            float2 o;
            o.x = acc[r].x + b.x;
            o.y = acc[r].y + b.y;
            *reinterpret_cast<float2*>(&Xs[(er0 + r) * XS_STRIDE + c0]) = o;
        }
    }

    // ---- vv-pass: a_vv stays in registers (acc) ----
    #pragma unroll
    for (int r = 0; r < 16; ++r) acc[r] = make_float2(0.f, 0.f);
    {
        const float* wp = mW2 + 2 * H + c0;          // cols [256,384)
        for (int k = 0; k < H; k += 4) {
            const float2 w0 = *reinterpret_cast<const float2*>(wp);
            const float2 w1 = *reinterpret_cast<const float2*>(wp + 3 * H);
            const float2 w2 = *reinterpret_cast<const float2*>(wp + 6 * H);
            const float2 w3 = *reinterpret_cast<const float2*>(wp + 9 * H);
            wp += 12 * H;
            #pragma unroll
            for (int r = 0; r < 16; ++r) {
                const float4 h = *reinterpret_cast<const float4*>(&H1s[(er0 + r) * H1_STRIDE + k]);
                acc[r].x += h.x * w0.x + h.y * w1.x + h.z * w2.x + h.w * w3.x;
                acc[r].y += h.x * w0.y + h.y * w1.y + h.z * w2.y + h.w * w3.y;
            }
        }
        const float2 b = *reinterpret_cast<const float2*>(mb2 + 2 * H + c0);
        #pragma unroll
        for (int r = 0; r < 16; ++r) {
            acc[r].x += b.x;
            acc[r].y += b.y;
        }
    }
    // own-wave H1s reads are done (program order) -> safe to overwrite below

    // ---- per d: msg = a_sv*evu_d + a_vv*v[src][d] -> H1s -> reduce -> agg_v ----
    #pragma unroll
    for (int d = 0; d < 3; ++d) {
        #pragma unroll
        for (int r = 0; r < 16; ++r) {
            const int row = er0 + r;
            const float ed = evus[row][d];
            const float2 asv = *reinterpret_cast<const float2*>(&Xs[row * XS_STRIDE + c0]);
            const float2 vv  = *reinterpret_cast<const float2*>(
                v + ((size_t)srcs[row] * 3 + d) * H + c0);
            float2 o;
            o.x = asv.x * ed + acc[r].x * vv.x;
            o.y = asv.y * ed + acc[r].y * vv.y;
            *reinterpret_cast<float2*>(&H1s[row * H1_STRIDE + c0]) = o;
        }
        __syncthreads();

        float run = 0.f;
        int prev = dsts[rr0];
        for (int r = rr0; r < rr0 + 32; ++r) {
            const int dn = dsts[r];
            if (dn != prev) {
                unsafeAtomicAdd(&agg_v[((size_t)prev * 3 + d) * H + rcol], run);
                run = 0.f; prev = dn;
            }
            run += H1s[r * H1_STRIDE + rcol];
        }
        unsafeAtomicAdd(&agg_v[((size_t)prev * 3 + d) * H + rcol], run);
        __syncthreads();
    }
}

__global__ __launch_bounds__(256, 1)
void painn_node_kernel(const float* __restrict__ s,
                       const float* __restrict__ v,
                       const float* __restrict__ uW1,
                       const float* __restrict__ ub1,
                       const float* __restrict__ uW2,
                       const float* __restrict__ ub2,
                       const float* __restrict__ ln_g,
                       const float* __restrict__ ln_b,
                       int N,
                       float* __restrict__ out_s,   // in: agg_s, out: s_out
                       float* __restrict__ out_v)   // in: agg_v, out: v_out
{
    __shared__ float Us[BN * US_STRIDE];   // [64][256+pad] : [s+agg_s | v_norm], later y
    __shared__ float H2s[BN * H2_STRIDE];

    const int t  = threadIdx.x;
    const int n0 = blockIdx.x * BN;
    const int m  = min(BN, N - n0);

    // ---- load s+agg_s and compute v_norm into Us ----
    #pragma unroll
    for (int it = 0; it < 8; ++it) {
        int idx = t + it * 256;
        int row = idx >> 5;
        int c4  = (idx & 31) << 2;
        if (row < m) {
            const int nb = (n0 + row) * H + c4;
            const float4 sv = *reinterpret_cast<const float4*>(s + nb);
            const float4 av = *reinterpret_cast<const float4*>(out_s + nb);
            float* p = &Us[row * US_STRIDE + c4];
            p[0] = sv.x + av.x; p[1] = sv.y + av.y;
            p[2] = sv.z + av.z; p[3] = sv.w + av.w;

            float nx = 0.f, ny = 0.f, nz = 0.f, nw = 0.f;
            #pragma unroll
            for (int d = 0; d < 3; ++d) {
                const int vb = ((n0 + row) * 3 + d) * H + c4;
                const float4 vv = *reinterpret_cast<const float4*>(v + vb);
                const float4 avv = *reinterpret_cast<const float4*>(out_v + vb);
                const float a0 = vv.x + avv.x, a1 = vv.y + avv.y;
                const float a2 = vv.z + avv.z, a3 = vv.w + avv.w;
                nx += a0 * a0; ny += a1 * a1; nz += a2 * a2; nw += a3 * a3;
            }
            float* q = &Us[row * US_STRIDE + H + c4];
            q[0] = sqrtf(nx); q[1] = sqrtf(ny); q[2] = sqrtf(nz); q[3] = sqrtf(nw);
        }
    }
    __syncthreads();

    const int ty = t >> 4;
    const int tx = t & 15;
    const int jb = tx << 3;
    const int nr = ty << 2;

    // ---- GEMV1: silu(upd_in @ uW1 + ub1) -> H2s ----
    {
        float acc[4][8];
        #pragma unroll
        for (int r2 = 0; r2 < 4; ++r2)
            #pragma unroll
            for (int j = 0; j < 8; ++j) acc[r2][j] = 0.f;

        const float* wp = uW1 + jb;
        for (int k = 0; k < 2 * H; ++k) {
            const float4 w0 = *reinterpret_cast<const float4*>(wp);
            const float4 w1 = *reinterpret_cast<const float4*>(wp + 4);
            wp += H;
            float uk[4];
            #pragma unroll
            for (int r2 = 0; r2 < 4; ++r2) uk[r2] = Us[(nr + r2) * US_STRIDE + k];
            #pragma unroll
            for (int r2 = 0; r2 < 4; ++r2) {
                acc[r2][0] += uk[r2] * w0.x;
                acc[r2][1] += uk[r2] * w0.y;
                acc[r2][2] += uk[r2] * w0.z;
                acc[r2][3] += uk[r2] * w0.w;
                acc[r2][4] += uk[r2] * w1.x;
                acc[r2][5] += uk[r2] * w1.y;
                acc[r2][6] += uk[r2] * w1.z;
                acc[r2][7] += uk[r2] * w1.w;
            }
        }
        const float4 b0 = *reinterpret_cast<const float4*>(ub1 + jb);
        const float4 b1 = *reinterpret_cast<const float4*>(ub1 + jb + 4);
        const float bias[8] = {b0.x, b0.y, b0.z, b0.w, b1.x, b1.y, b1.z, b1.w};
        #pragma unroll
        for (int r2 = 0; r2 < 4; ++r2)
            #pragma unroll
            for (int j = 0; j < 8; ++j)
                H2s[(nr + r2) * H2_STRIDE + jb + j] = silu_f(acc[r2][j] + bias[j]);
    }
    __syncthreads();

    // ---- GEMV2: delta_s & gate; y = s + delta_s into Us ----
    float gate[4][8];
    {
        float ad[4][8], ag[4][8];
        #pragma unroll
        for (int r2 = 0; r2 < 4; ++r2)
            #pragma unroll
            for (int j = 0; j < 8; ++j) { ad[r2][j] = 0.f; ag[r2][j] = 0.f; }

        const float* wp = uW2 + jb;
        for (int k = 0; k < H; ++k) {
            const float4 d0 = *reinterpret_cast<const float4*>(wp);
            const float4 d1 = *reinterpret_cast<const float4*>(wp + 4);
            const float4 g0 = *reinterpret_cast<const float4*>(wp + H);
            const float4 g1 = *reinterpret_cast<const float4*>(wp + H + 4);
            wp += 2 * H;
            float hk[4];
            #pragma unroll
            for (int r2 = 0; r2 < 4; ++r2) hk[r2] = H2s[(nr + r2) * H2_STRIDE + k];
            #pragma unroll
            for (int r2 = 0; r2 < 4; ++r2) {
                ad[r2][0] += hk[r2] * d0.x;  ag[r2][0] += hk[r2] * g0.x;
                ad[r2][1] += hk[r2] * d0.y;  ag[r2][1] += hk[r2] * g0.y;
                ad[r2][2] += hk[r2] * d0.z;  ag[r2][2] += hk[r2] * g0.z;
                ad[r2][3] += hk[r2] * d0.w;  ag[r2][3] += hk[r2] * g0.w;
                ad[r2][4] += hk[r2] * d1.x;  ag[r2][4] += hk[r2] * g1.x;
                ad[r2][5] += hk[r2] * d1.y;  ag[r2][5] += hk[r2] * g1.y;
                ad[r2][6] += hk[r2] * d1.z;  ag[r2][6] += hk[r2] * g1.z;
                ad[r2][7] += hk[r2] * d1.w;  ag[r2][7] += hk[r2] * g1.w;
            }
        }
        const float4 bd0 = *reinterpret_cast<const float4*>(ub2 + jb);
        const float4 bd1 = *reinterpret_cast<const float4*>(ub2 + jb + 4);
        const float4 bg0 = *reinterpret_cast<const float4*>(ub2 + H + jb);
        const float4 bg1 = *reinterpret_cast<const float4*>(ub2 + H + jb + 4);
        const float bd[8] = {bd0.x, bd0.y, bd0.z, bd0.w, bd1.x, bd1.y, bd1.z, bd1.w};
        const float bg[8] = {bg0.x, bg0.y, bg0.z, bg0.w, bg1.x, bg1.y, bg1.z, bg1.w};

        #pragma unroll
        for (int r2 = 0; r2 < 4; ++r2) {
            #pragma unroll
            for (int j = 0; j < 8; ++j) gate[r2][j] = ag[r2][j] + bg[j];
            if (nr + r2 < m) {
                const int nb = (n0 + nr + r2) * H + jb;
                const float4 s0 = *reinterpret_cast<const float4*>(s + nb);
                const float4 s1 = *reinterpret_cast<const float4*>(s + nb + 4);
                const float sl[8] = {s0.x, s0.y, s0.z, s0.w, s1.x, s1.y, s1.z, s1.w};
                float* yp = &Us[(nr + r2) * US_STRIDE + jb];
                #pragma unroll
                for (int j = 0; j < 8; ++j) yp[j] = sl[j] + ad[r2][j] + bd[j];
            }
        }
    }
    __syncthreads();

    // ---- LayerNorm on y (4 threads per row) -> s_out ----
    {
        const int row = t >> 2;
        const int q   = t & 3;
        if (row < m) {
            float sum = 0.f, ss = 0.f;
            #pragma unroll
            for (int i = 0; i < 32; ++i) {
                const float val = Us[row * US_STRIDE + q * 32 + i];
                sum += val; ss += val * val;
            }
            sum += __shfl_xor(sum, 1); ss += __shfl_xor(ss, 1);
            sum += __shfl_xor(sum, 2); ss += __shfl_xor(ss, 2);
            const float mu   = sum * (1.0f / H);
            const float var  = ss * (1.0f / H) - mu * mu;
            const float rstd = rsqrtf(fmaxf(var, 0.f) + LN_EPS);
            #pragma unroll
            for (int i4 = 0; i4 < 8; ++i4) {
                const int c = q * 32 + i4 * 4;
                const float4 g = *reinterpret_cast<const float4*>(ln_g + c);
                const float4 b = *reinterpret_cast<const float4*>(ln_b + c);
                const float* yp = &Us[row * US_STRIDE + c];
                float4 o;
                o.x = (yp[0] - mu) * rstd * g.x + b.x;
                o.y = (yp[1] - mu) * rstd * g.y + b.y;
                o.z = (yp[2] - mu) * rstd * g.z + b.z;
                o.w = (yp[3] - mu) * rstd * g.w + b.w;
                *reinterpret_cast<float4*>(out_s + (n0 + row) * H + c) = o;
            }
        }
    }

    // ---- v_out = gate * (v + agg_v), in place over agg_v ----
    #pragma unroll
    for (int r2 = 0; r2 < 4; ++r2) {
        if (nr + r2 < m) {
            const int nn = n0 + nr + r2;
            #pragma unroll
            for (int d = 0; d < 3; ++d) {
                const int vb = (nn * 3 + d) * H + jb;
                const float4 vv0 = *reinterpret_cast<const float4*>(v + vb);
                const float4 vv1 = *reinterpret_cast<const float4*>(v + vb + 4);
                const float4 av0 = *reinterpret_cast<const float4*>(out_v + vb);
                const float4 av1 = *reinterpret_cast<const float4*>(out_v + vb + 4);
                float4 o0, o1;
                o0.x = gate[r2][0] * (vv0.x + av0.x);
                o0.y = gate[r2][1] * (vv0.y + av0.y);
                o0.z = gate[r2][2] * (vv0.z + av0.z);
                o0.w = gate[r2][3] * (vv0.w + av0.w);
                o1.x = gate[r2][4] * (vv1.x + av1.x);
                o1.y = gate[r2][5] * (vv1.y + av1.y);
                o1.z = gate[r2][6] * (vv1.z + av1.z);
                o1.w = gate[r2][7] * (vv1.w + av1.w);
                *reinterpret_cast<float4*>(out_v + vb)     = o0;
                *reinterpret_cast<float4*>(out_v + vb + 4) = o1;
            }
        }
    }
}

extern "C" void kernel_launch(void* const* d_in, const int* in_sizes, int n_in,
                              void* d_out, int out_size, void* d_ws, size_t ws_size,
                              hipStream_t stream)
{
    const float* s    = (const float*)d_in[0];
    const float* v    = (const float*)d_in[1];
    const float* rbf  = (const float*)d_in[2];
    const float* evu  = (const float*)d_in[3];
    const float* mW1  = (const float*)d_in[4];
    const float* mb1  = (const float*)d_in[5];
    const float* mW2  = (const float*)d_in[6];
    const float* mb2  = (const float*)d_in[7];
    const float* uW1  = (const float*)d_in[8];
    const float* ub1  = (const float*)d_in[9];
    const float* uW2  = (const float*)d_in[10];
    const float* ub2  = (const float*)d_in[11];
    const float* ln_g = (const float*)d_in[12];
    const float* ln_b = (const float*)d_in[13];
    const int*   eidx = (const int*)d_in[14];

    const int N = in_sizes[0] / H;   // 50000
    const int E = in_sizes[2] / R;   // 800000

    float* agg_s = (float*)d_out;                 // [N,H]
    float* agg_v = (float*)d_out + (size_t)N * H; // [N,3,H]

    // workspace layout: cnt[N] | fill[N] | sorted[E]  (~3.6 MB)
    int* cnt    = (int*)d_ws;
    int* fill   = cnt + N;
    int* sorted = fill + N;

    // zero agg buffers (d_out re-poisoned to 0xAA before every call) + counters
    const long n4 = (long)N * 4 * H / 4;          // float4 count
    zero_f4_kernel<<<dim3(2048), dim3(256), 0, stream>>>((float4*)d_out, n4);
    zero_i_kernel<<<dim3(64), dim3(256), 0, stream>>>(cnt, N);

    // counting sort of edges by destination
    hist_kernel<<<dim3(2048), dim3(256), 0, stream>>>(eidx, E, cnt);
    scan_kernel<<<dim3(1), dim3(1024), 0, stream>>>(cnt, N, fill);
    scatter_kernel<<<dim3(2048), dim3(256), 0, stream>>>(eidx, E, fill, sorted);

    painn_edge_kernel<<<dim3(E / BE), dim3(256), 0, stream>>>(
        s, v, rbf, evu, mW1, mb1, mW2, mb2, eidx, sorted, E, agg_s, agg_v);

    painn_node_kernel<<<dim3((N + BN - 1) / BN), dim3(256), 0, stream>>>(
        s, v, uW1, ub1, uW2, ub2, ln_g, ln_b, N, agg_s, agg_v);
}